// Round 12
// baseline (98.081 us; speedup 1.0000x reference)
//
#include <hip/hip_runtime.h>
#include <math.h>

typedef unsigned int uint;
typedef unsigned short u16;
typedef unsigned long long u64;

#define NT 256
#define KTOP 200
#define CAP 256      // final candidate cap == NT (rank-sort)
#define CAPC 3072    // LDS candidate-list cap
#define SEGS 4       // collect segments per task
#define SEGCAP 512   // per-segment candidate cap in global
#define NCLS 21
#define C1 20
#define MROWS 208
#define NSPLIT 48    // prep blocks per batch image

__device__ __forceinline__ u64 flip64(double d) {
  u64 u = (u64)__double_as_longlong(d);
  return (u & 0x8000000000000000ULL) ? ~u : (u | 0x8000000000000000ULL);
}

__device__ __forceinline__ double unflip64(u64 k) {
  u64 u = (k & 0x8000000000000000ULL) ? (k ^ 0x8000000000000000ULL) : ~k;
  return __longlong_as_double((long long)u);
}

// monotone u16 fixed-point key for s = log prob; 0 = invalid
__device__ __forceinline__ uint q_key16(float sf) {
  float qf = (sf + 16.0f) * 4096.0f;
  qf = fmaxf(fminf(qf, 65535.0f), 1.0f);
  return (uint)qf;
}

// parallel 256-bin suffix-scan walk: bin = max j with S[j] >= rank.
__device__ __forceinline__ void par_walk(const uint* hist, uint* scan, u64* wm,
                                         uint* res, uint rank, int tid) {
  scan[tid] = hist[tid];
  __syncthreads();
#pragma unroll
  for (int off = 1; off < 256; off <<= 1) {
    uint v = scan[tid];
    uint a = (tid + off < 256) ? scan[tid + off] : 0u;
    __syncthreads();
    scan[tid] = v + a;
    __syncthreads();
  }
  u64 m = __ballot(scan[tid] >= rank);
  if ((tid & 63) == 0) wm[tid >> 6] = m;
  __syncthreads();
  if (tid == 0) {
    int bin = 0;
    for (int w = 3; w >= 0; --w) {
      if (wm[w]) { bin = w * 64 + (63 - __clzll(wm[w])); break; }
    }
    res[0] = (uint)bin;
    res[1] = scan[bin];
    res[2] = hist[bin];
  }
  __syncthreads();
}

// ---- K1: LSE (hw f32 exp, f64 accum) + u16 keys + dense per-slice hist -------
__global__ __launch_bounds__(NT) void prep_kernel(
    const float* __restrict__ scores, const float* __restrict__ conf_th,
    double* __restrict__ lse_out, u16* __restrict__ keys_out,
    uint* __restrict__ ghist,     // [B*NSPLIT*C1, 256] dense slices
    int B, int N, int npad, int perblk)
{
  __shared__ double s_logth[C1];
  __shared__ uint lhist[C1 * 256];
  int tid = threadIdx.x;
  if (tid < C1) s_logth[tid] = log((double)conf_th[tid]);
  for (int i = tid; i < C1 * 256; i += NT) lhist[i] = 0;
  __syncthreads();

  int b = blockIdx.x / NSPLIT, j = blockIdx.x - b * NSPLIT;
  int s0 = j * perblk, e0 = min(N, s0 + perblk);

  for (int n = s0 + tid; n < e0; n += NT) {
    int gid = b * N + n;
    const float* sc = scores + (size_t)b * NCLS * N + n;
    float v[NCLS];
    float mx = -INFINITY;
#pragma unroll
    for (int c = 0; c < NCLS; ++c) { v[c] = sc[(size_t)c * N]; mx = fmaxf(mx, v[c]); }
    double sum0 = 0.0, sum1 = 0.0, sum2 = 0.0;
#pragma unroll
    for (int c = 0; c < NCLS; ++c) {
      float e = __expf(v[c] - mx);
      if ((c % 3) == 0) sum0 += (double)e;
      else if ((c % 3) == 1) sum1 += (double)e;
      else sum2 += (double)e;
    }
    double lse = (double)mx + log(sum0 + sum1 + sum2);
    lse_out[gid] = lse;

#pragma unroll
    for (int c = 0; c < C1; ++c) {
      double s = (double)v[c + 1] - lse;
      uint key = 0;
      if (s > s_logth[c]) key = q_key16((float)s);
      keys_out[((size_t)b * C1 + c) * npad + n] = (u16)key;
      if (key) atomicAdd(&lhist[c * 256 + (key >> 8)], 1u);
    }
  }
  if (j == NSPLIT - 1 && npad > N) {
    int pad = npad - N;
    for (int t = tid; t < pad * C1; t += NT) {
      int c = t / pad, n = N + (t - c * pad);
      keys_out[((size_t)b * C1 + c) * npad + n] = 0;
    }
  }
  __syncthreads();
  // dense slice store: every entry written -> no zero-init of ghist needed
  uint* gslice = ghist + (size_t)(b * NSPLIT + j) * C1 * 256;
  for (int i = tid; i < C1 * 256; i += NT) gslice[i] = lhist[i];
}

// ---- K2: per-task slice-sum + suffix-scan walk -> L0cnt ----------------------
__global__ __launch_bounds__(64) void walk_kernel(
    const uint* __restrict__ ghist, uint4* __restrict__ L0cnt, int B)
{
  int task = blockIdx.x;
  int b = task / C1, c = task - b * C1;
  int lane = threadIdx.x;
  uint4 h = make_uint4(0, 0, 0, 0);
  for (int j = 0; j < NSPLIT; ++j) {
    const uint4* sl = reinterpret_cast<const uint4*>(
        ghist + ((size_t)(b * NSPLIT + j) * C1 + c) * 256);
    uint4 t = sl[lane];
    h.x += t.x; h.y += t.y; h.z += t.z; h.w += t.w;
  }
  uint s = h.x + h.y + h.z + h.w;
  uint suf = s;
#pragma unroll
  for (int off = 1; off < 64; off <<= 1) {
    uint o = (uint)__shfl_down((int)suf, off);
    if (lane + off < 64) suf += o;
  }
  uint total = (uint)__shfl((int)suf, 0);
  uint sn = (uint)__shfl_down((int)suf, 1);
  if (lane == 63) sn = 0;
  uint c3 = h.w + sn, c2 = c3 + h.z, c1 = c2 + h.y, c0 = c1 + h.x;
  uint binoff, cnt, abv;
  if (c3 >= KTOP)      { binoff = 3; cnt = c3; abv = c3 - h.w; }
  else if (c2 >= KTOP) { binoff = 2; cnt = c2; abv = c2 - h.z; }
  else if (c1 >= KTOP) { binoff = 1; cnt = c1; abv = c1 - h.y; }
  else                 { binoff = 0; cnt = c0; abv = c0 - h.x; }
  uint L0v, cnt0v, abovev;
  if (total < KTOP) {
    L0v = 1u; cnt0v = total; abovev = 0u;
  } else {
    u64 m = __ballot(suf >= KTOP);
    int l = 63 - __clzll(m);
    uint bo = (uint)__shfl((int)binoff, l);
    cnt0v = (uint)__shfl((int)cnt, l);
    abovev = (uint)__shfl((int)abv, l);
    L0v = ((uint)(4 * l) + bo) << 8;
  }
  if (lane == 0) L0cnt[task] = make_uint4(L0v, cnt0v, abovev, total);
}

// ---- K3: distributed collect (B*C1*SEGS blocks, u16 keys) --------------------
__global__ __launch_bounds__(NT) void collect_kernel(
    const u16* __restrict__ keys, const uint4* __restrict__ L0cnt,
    uint* __restrict__ cand, uint* __restrict__ cnts, int npad)
{
  int blk = blockIdx.x;
  int task = blk >> 2, seg = blk & (SEGS - 1);
  int tid = threadIdx.x, lane = tid & 63;
  __shared__ uint sCnt;
  if (tid == 0) sCnt = 0;
  __syncthreads();

  uint4 w0 = L0cnt[task];
  uint L = w0.x, cnt0 = w0.y;
  if (cnt0 > CAPC) { if (tid == 0) cnts[blk] = 0; return; }   // slow path in F1

  const u16* krow = keys + (size_t)task * npad;
  const uint4* krow8 = reinterpret_cast<const uint4*>(krow);
  int nv8 = npad >> 3;
  int per8 = (nv8 + SEGS - 1) >> 2;
  int s8 = seg * per8, e8 = min(nv8, s8 + per8);
  uint* myc = cand + ((size_t)task * SEGS + seg) * SEGCAP;

  for (int i = s8 + tid; i < e8; i += NT) {
    uint4 kv = krow8[i];
    uint base = (uint)(i << 3);
    uint ks[8] = { kv.x & 0xFFFFu, kv.x >> 16, kv.y & 0xFFFFu, kv.y >> 16,
                   kv.z & 0xFFFFu, kv.z >> 16, kv.w & 0xFFFFu, kv.w >> 16 };
#pragma unroll
    for (int comp = 0; comp < 8; ++comp) {
      uint k = ks[comp];
      bool f = (k >= L);
      u64 m = __ballot(f);
      if (m) {
        uint nb = (uint)__popcll(m);
        uint wb = 0;
        if (lane == 0) wb = atomicAdd(&sCnt, nb);
        wb = (uint)__shfl((int)wb, 0);
        if (f) {
          uint pos = wb + (uint)__popcll(m & ((1ULL << lane) - 1ULL));
          if (pos < SEGCAP) myc[pos] = (k << 15) | (base + comp);
        }
      }
    }
  }
  __syncthreads();
  if (tid == 0) cnts[blk] = sCnt;      // actual (uncapped) count
}

// ---- F1: narrow -> gather (decode boxes inline) -> rank-sort -> write top-K --
__global__ __launch_bounds__(NT) void topk_kernel(
    const u16* __restrict__ keys, const uint4* __restrict__ L0cnt,
    const uint* __restrict__ candg, const uint* __restrict__ cnts,
    const float* __restrict__ scores, const double* __restrict__ lse,
    const float* __restrict__ bboxes, const float* __restrict__ dboxes,
    const float* __restrict__ scale_xy_p, const float* __restrict__ scale_wh_p,
    u64* __restrict__ tkeys, float4* __restrict__ tbox, uint* __restrict__ tcnt,
    int B, int N, int npad)
{
  int task = blockIdx.x;
  int b = task / C1, c = task - b * C1;
  int tid = threadIdx.x, lane = tid & 63;
  const u16* krow = keys + (size_t)task * npad;
  int nv8 = npad >> 3;

  __shared__ uint cand[CAPC];            // 12 KB
  __shared__ uint histB[256];
  __shared__ uint scanB[256];
  __shared__ u64 wmB[4];
  __shared__ uint res3[4];
  __shared__ uint scq[SEGS];
  __shared__ int si[CAP];
  __shared__ u64 sC[CAP];
  __shared__ float4 sbx[CAP];
  __shared__ uint sCnt, sCnt2;

  uint4 w0 = L0cnt[task];
  uint cnt0 = w0.y;
  if (tid < SEGS) scq[tid] = cnts[task * SEGS + tid];
  if (tid == 0) { sCnt = 0; sCnt2 = 0; }
  __syncthreads();
  bool slow = (cnt0 > CAPC) ||
              (scq[0] > SEGCAP) || (scq[1] > SEGCAP) ||
              (scq[2] > SEGCAP) || (scq[3] > SEGCAP);

  uint pref = w0.x >> 8, above = w0.z, rank = KTOP - w0.z;
  uint cnt;

  if (!slow) {
    uint off1 = scq[0], off2 = off1 + scq[1], off3 = off2 + scq[2];
    cnt = off3 + scq[3];
    const uint* cg = candg + (size_t)task * SEGS * SEGCAP;
    for (int j = tid; j < (int)scq[0]; j += NT) cand[j] = cg[j];
    for (int j = tid; j < (int)scq[1]; j += NT) cand[off1 + j] = cg[SEGCAP + j];
    for (int j = tid; j < (int)scq[2]; j += NT) cand[off2 + j] = cg[2 * SEGCAP + j];
    for (int j = tid; j < (int)scq[3]; j += NT) cand[off3 + j] = cg[3 * SEGCAP + j];
    __syncthreads();
  } else {
    const uint4* krow8 = reinterpret_cast<const uint4*>(krow);
    histB[tid] = 0;
    __syncthreads();
    for (int i = tid; i < nv8; i += NT) {
      uint4 kv = krow8[i];
      uint ks[8] = { kv.x & 0xFFFFu, kv.x >> 16, kv.y & 0xFFFFu, kv.y >> 16,
                     kv.z & 0xFFFFu, kv.z >> 16, kv.w & 0xFFFFu, kv.w >> 16 };
#pragma unroll
      for (int comp = 0; comp < 8; ++comp) {
        uint k = ks[comp];
        if ((k >> 8) == pref) atomicAdd(&histB[k & 255u], 1u);
      }
    }
    __syncthreads();
    par_walk(histB, scanB, wmB, res3, rank, tid);
    uint Ts = (pref << 8) | res3[0];
    for (int i = tid; i < nv8; i += NT) {
      uint4 kv = krow8[i];
      uint base = (uint)(i << 3);
      uint ks[8] = { kv.x & 0xFFFFu, kv.x >> 16, kv.y & 0xFFFFu, kv.y >> 16,
                     kv.z & 0xFFFFu, kv.z >> 16, kv.w & 0xFFFFu, kv.w >> 16 };
#pragma unroll
      for (int comp = 0; comp < 8; ++comp) {
        uint k = ks[comp];
        bool f = (k >= Ts);
        u64 m = __ballot(f);
        if (m) {
          uint nb = (uint)__popcll(m);
          uint wb = 0;
          if (lane == 0) wb = atomicAdd(&sCnt, nb);
          wb = (uint)__shfl((int)wb, 0);
          if (f) {
            uint pos = wb + (uint)__popcll(m & ((1ULL << lane) - 1ULL));
            if (pos < CAPC) cand[pos] = (k << 15) | (base + comp);
          }
        }
      }
    }
    __syncthreads();
    cnt = min(sCnt, (uint)CAPC);
  }

  // ---------- narrow candidate list to <= CAP (one 256-bin level, exact key)
  uint cntF;
  if (cnt <= CAP) {
    for (int p = tid; p < (int)cnt; p += NT) si[p] = (int)(cand[p] & 0x7FFFu);
    __syncthreads();
    cntF = cnt;
  } else {
    histB[tid] = 0;
    __syncthreads();
    for (int p = tid; p < (int)cnt; p += NT) {
      uint k = cand[p] >> 15;
      if ((k >> 8) == pref) atomicAdd(&histB[k & 255u], 1u);
    }
    __syncthreads();
    par_walk(histB, scanB, wmB, res3, rank, tid);
    uint T = (pref << 8) | res3[0];
    for (int p = tid; p < (int)cnt; p += NT) {
      uint cd = cand[p];
      if ((cd >> 15) >= T) {
        uint q = atomicAdd(&sCnt2, 1u);
        if (q < CAP) si[q] = (int)(cd & 0x7FFFu);
      }
    }
    __syncthreads();
    cntF = min(sCnt2, (uint)CAP);
  }

  // ---------- gather f64 score + decode box inline; composite key
  {
    float sxy = *scale_xy_p, swh = *scale_wh_p;
    int p = tid;
    u64 C;
    if (p < (int)cntF) {
      int n = si[p];
      double s = (double)scores[((size_t)b * NCLS + (c + 1)) * N + n] - lse[(size_t)b * N + n];
      u64 f = flip64(s);
      C = (f & ~0x7FFFULL) | (u64)(32767 - n);
      const float* bb = bboxes + (size_t)b * 4 * N + n;
      float bx = bb[0];
      float by = bb[(size_t)N];
      float bw = bb[2 * (size_t)N];
      float bh = bb[3 * (size_t)N];
      float4 d = reinterpret_cast<const float4*>(dboxes)[n];
      float x = sxy * bx * d.z + d.x;
      float y = sxy * by * d.w + d.y;
      float w = expf(swh * bw) * d.z;
      float h = expf(swh * bh) * d.w;
      sbx[p] = make_float4(x - 0.5f * w, y - 0.5f * h, x + 0.5f * w, y + 0.5f * h);
    } else {
      C = (u64)p;
      sbx[p] = make_float4(0.f, 0.f, 0.f, 0.f);
    }
    sC[p] = C;
  }
  __syncthreads();

  // ---------- rank-sort: single u64 compare (keys all distinct)
  {
    u64 kp = sC[tid];
    int r = 0;
#pragma unroll 8
    for (int jj = 0; jj < CAP; ++jj) r += (sC[jj] > kp) ? 1 : 0;
    if (r < KTOP) {
      tkeys[(size_t)task * KTOP + r] = kp;
      tbox[(size_t)task * KTOP + r] = sbx[tid];
    }
  }
  if (tid == 0) tcnt[task] = min(cntF, (uint)KTOP);
}

// ---- F2: register-blocked mask + 1-wave resolve + output --------------------
__global__ __launch_bounds__(NT) void maskresolve_kernel(
    const u64* __restrict__ tkeys, const float4* __restrict__ tbox,
    const uint* __restrict__ tcnt, const float* __restrict__ nms_th_p,
    float* __restrict__ out, int B)
{
  int task = blockIdx.x;
  int b = task / C1, c = task - b * C1;
  int tid = threadIdx.x, lane = tid & 63, wav = tid >> 6;

  __shared__ float4 sbox[MROWS];
  __shared__ float sar[MROWS];
  __shared__ u64 smaskT[13][64];
  __shared__ u64 saliveW[4];

  int valid = (int)tcnt[task];
  float nth = *nms_th_p;

  if (tid < MROWS) {
    float4 bx = (tid < valid) ? tbox[(size_t)task * KTOP + tid]
                              : make_float4(0.f, 0.f, 0.f, 0.f);
    sbox[tid] = bx;
    sar[tid] = fmaxf(bx.z - bx.x, 0.f) * fmaxf(bx.w - bx.y, 0.f);
  }
  __syncthreads();

  {
    float4 jb0 = sbox[lane], jb1 = sbox[lane + 64], jb2 = sbox[lane + 128];
    float4 jb3 = (lane + 192 < MROWS) ? sbox[lane + 192]
                                      : make_float4(0.f, 0.f, 0.f, 0.f);
    float ja0 = sar[lane], ja1 = sar[lane + 64], ja2 = sar[lane + 128],
          ja3 = (lane + 192 < MROWS) ? sar[lane + 192] : 0.f;
    for (int w = wav; w < 13; w += 4) {
      u64 word = 0;
      int r0 = w * 16;
#pragma unroll
      for (int rr = 0; rr < 16; ++rr) {
        int r = r0 + rr;
        float4 rb = sbox[r];
        float ra = sar[r];
        uint nib = 0;
#define IOU_BIT(K, JB, JA) { \
        int j = lane + 64 * (K); \
        float xx1 = fmaxf(rb.x, JB.x), yy1 = fmaxf(rb.y, JB.y); \
        float xx2 = fminf(rb.z, JB.z), yy2 = fminf(rb.w, JB.w); \
        float ww = fmaxf(xx2 - xx1, 0.f), hh = fmaxf(yy2 - yy1, 0.f); \
        float inter = ww * hh; \
        float den = ((ra + JA) - inter) + 1e-9f; \
        if ((inter >= nth * den) && (j > r)) nib |= 1u << (K); }
        IOU_BIT(0, jb0, ja0) IOU_BIT(1, jb1, ja1)
        IOU_BIT(2, jb2, ja2) IOU_BIT(3, jb3, ja3)
#undef IOU_BIT
        word |= (u64)nib << (rr * 4);
      }
      smaskT[w][lane] = word;
    }
  }
  __syncthreads();

  if (tid < 64) {
    u64 mm[13];
#pragma unroll
    for (int w = 0; w < 13; ++w) mm[w] = smaskT[w][lane];
    uint av = 0;
#pragma unroll
    for (int k = 0; k < 4; ++k)
      if (lane + 64 * k < valid) av |= 1u << k;
#define STEP(i) { \
    u64 bm = __ballot((lane == ((i) & 63)) && ((av >> ((i) >> 6)) & 1u)); \
    if (bm) av &= ~((uint)((mm[(i) >> 4] >> (((i) & 15) * 4)) & 0xFULL)); }
#define S4(i)  STEP(i) STEP((i)+1) STEP((i)+2) STEP((i)+3)
#define S16(i) S4(i) S4((i)+4) S4((i)+8) S4((i)+12)
#define S64(i) S16(i) S16((i)+16) S16((i)+32) S16((i)+48)
    S64(0) S64(64) S64(128) S16(192)
#undef S64
#undef S16
#undef S4
#undef STEP
#pragma unroll
    for (int k = 0; k < 4; ++k) {
      u64 bb = __ballot((av >> k) & 1u);
      if (lane == 0) saliveW[k] = bb;
    }
  }
  __syncthreads();

  size_t M = (size_t)C1 * KTOP;
  float* out_boxes  = out;
  float* out_labels = out + (size_t)B * M * 4;
  float* out_scores = out_labels + (size_t)B * M;
  float* out_keep   = out_scores + (size_t)B * M;
  if (tid < KTOP) {
    size_t slot = ((size_t)b * C1 + c) * KTOP + tid;
    bool kept = (tid < valid) && ((saliveW[tid >> 6] >> (tid & 63)) & 1ULL);
    float4 bx = kept ? sbox[tid] : make_float4(0.f, 0.f, 0.f, 0.f);
    reinterpret_cast<float4*>(out_boxes)[slot] = bx;
    out_labels[slot] = kept ? (float)(c + 1) : 0.0f;
    out_scores[slot] = kept ? (float)exp(unflip64(tkeys[(size_t)task * KTOP + tid])) : 0.0f;
    out_keep[slot]   = kept ? 1.0f : 0.0f;
  }
}

extern "C" void kernel_launch(void* const* d_in, const int* in_sizes, int n_in,
                              void* d_out, int out_size, void* d_ws, size_t ws_size,
                              hipStream_t stream) {
  const float* bboxes   = (const float*)d_in[0];
  const float* scores   = (const float*)d_in[1];
  const float* dboxes   = (const float*)d_in[2];
  const float* conf_th  = (const float*)d_in[3];
  const float* nms_th   = (const float*)d_in[4];
  const float* scale_xy = (const float*)d_in[6];
  const float* scale_wh = (const float*)d_in[7];

  int N = in_sizes[2] / 4;
  int B = in_sizes[0] / (4 * N);
  int npad = (N + 7) & ~7;

  // ws: lse | keys(u16) | ghist(dense slices) | L0cnt | cand(u32) | cnts | tkeys | tbox | tcnt
  char* ws = (char*)d_ws;
  size_t off = 0;
  double* lse     = (double*)(ws + off); off += (size_t)B * N * 8;
  u16*    keys    = (u16*)   (ws + off); off += (size_t)B * C1 * npad * 2;
  uint*   ghist   = (uint*)  (ws + off); off += (size_t)B * NSPLIT * C1 * 256 * 4;
  uint4*  L0cnt   = (uint4*) (ws + off); off += (size_t)B * C1 * 16;
  uint*   cand    = (uint*)  (ws + off); off += (size_t)B * C1 * SEGS * SEGCAP * 4;
  uint*   cnts    = (uint*)  (ws + off); off += (size_t)B * C1 * SEGS * 4;
  u64*    tkeys   = (u64*)   (ws + off); off += (size_t)B * C1 * KTOP * 8;
  float4* tbox    = (float4*)(ws + off); off += (size_t)B * C1 * KTOP * 16;
  uint*   tcnt    = (uint*)  (ws + off);

  int perblk = (N + NSPLIT - 1) / NSPLIT;
  prep_kernel<<<B * NSPLIT, NT, 0, stream>>>(
      scores, conf_th, lse, keys, ghist, B, N, npad, perblk);

  walk_kernel<<<B * C1, 64, 0, stream>>>(ghist, L0cnt, B);

  collect_kernel<<<B * C1 * SEGS, NT, 0, stream>>>(
      keys, L0cnt, cand, cnts, npad);

  topk_kernel<<<B * C1, NT, 0, stream>>>(
      keys, L0cnt, cand, cnts, scores, lse, bboxes, dboxes,
      scale_xy, scale_wh, tkeys, tbox, tcnt, B, N, npad);

  maskresolve_kernel<<<B * C1, NT, 0, stream>>>(
      tkeys, tbox, tcnt, nms_th, (float*)d_out, B);
}

// Round 13
// 93.555 us; speedup vs baseline: 1.0484x; 1.0484x over previous
//
#include <hip/hip_runtime.h>
#include <math.h>

typedef unsigned int uint;
typedef unsigned short u16;
typedef unsigned long long u64;

#define NT 256
#define KTOP 200
#define CAP 256      // final candidate cap == NT (rank-sort)
#define CAPC 3072    // LDS candidate-list cap
#define SEGS 4       // collect segments per task
#define SEGCAP 512   // per-segment candidate cap in global
#define NCLS 21
#define C1 20
#define MROWS 208
#define NSPLIT 48    // prep blocks per batch image

__device__ __forceinline__ u64 flip64(double d) {
  u64 u = (u64)__double_as_longlong(d);
  return (u & 0x8000000000000000ULL) ? ~u : (u | 0x8000000000000000ULL);
}

__device__ __forceinline__ double unflip64(u64 k) {
  u64 u = (k & 0x8000000000000000ULL) ? (k ^ 0x8000000000000000ULL) : ~k;
  return __longlong_as_double((long long)u);
}

// monotone u16 fixed-point key for s = log prob; 0 = invalid
__device__ __forceinline__ uint q_key16(float sf) {
  float qf = (sf + 16.0f) * 4096.0f;
  qf = fmaxf(fminf(qf, 65535.0f), 1.0f);
  return (uint)qf;
}

// parallel 256-bin suffix-scan walk: bin = max j with S[j] >= rank.
__device__ __forceinline__ void par_walk(const uint* hist, uint* scan, u64* wm,
                                         uint* res, uint rank, int tid) {
  scan[tid] = hist[tid];
  __syncthreads();
#pragma unroll
  for (int off = 1; off < 256; off <<= 1) {
    uint v = scan[tid];
    uint a = (tid + off < 256) ? scan[tid + off] : 0u;
    __syncthreads();
    scan[tid] = v + a;
    __syncthreads();
  }
  u64 m = __ballot(scan[tid] >= rank);
  if ((tid & 63) == 0) wm[tid >> 6] = m;
  __syncthreads();
  if (tid == 0) {
    int bin = 0;
    for (int w = 3; w >= 0; --w) {
      if (wm[w]) { bin = w * 64 + (63 - __clzll(wm[w])); break; }
    }
    res[0] = (uint)bin;
    res[1] = scan[bin];
    res[2] = hist[bin];
  }
  __syncthreads();
}

// ---- K0: zero the compact hist (640 KB; replaces pathological rocclr fill) --
__global__ __launch_bounds__(NT) void zero_ghist(uint* __restrict__ g) {
  g[(size_t)blockIdx.x * NT + threadIdx.x] = 0;
}

// ---- K1: LSE + u16 keys, 2 anchors/thread, compact-ghist atomics ------------
__global__ __launch_bounds__(NT) void prep_kernel(
    const float* __restrict__ scores, const float* __restrict__ conf_th,
    double* __restrict__ lse_out, u16* __restrict__ keys_out,
    uint* __restrict__ ghist,     // [B*C1, 256] compact
    int B, int N, int npad, int perblk)
{
  __shared__ double s_logth[C1];
  __shared__ uint lhist[C1 * 256];
  int tid = threadIdx.x;
  if (tid < C1) s_logth[tid] = log((double)conf_th[tid]);
  for (int i = tid; i < C1 * 256; i += NT) lhist[i] = 0;
  __syncthreads();

  int b = blockIdx.x / NSPLIT, j = blockIdx.x - b * NSPLIT;
  int s0 = j * perblk, e0 = min(N, s0 + perblk);
  int half = (e0 - s0) >> 1;          // perblk, s0, e0 all even

  for (int p = tid; p < half; p += NT) {
    int n = s0 + 2 * p;
    const float* sc = scores + (size_t)b * NCLS * N + n;
    float2 v[NCLS];
    float mx0 = -INFINITY, mx1 = -INFINITY;
#pragma unroll
    for (int c = 0; c < NCLS; ++c) {
      float2 t = *reinterpret_cast<const float2*>(sc + (size_t)c * N);
      v[c] = t;
      mx0 = fmaxf(mx0, t.x);
      mx1 = fmaxf(mx1, t.y);
    }
    double a0 = 0.0, a1 = 0.0, a2 = 0.0;   // anchor 0 accumulators
    double b0 = 0.0, b1 = 0.0, b2 = 0.0;   // anchor 1 accumulators
#pragma unroll
    for (int c = 0; c < NCLS; ++c) {
      float e0f = __expf(v[c].x - mx0);
      float e1f = __expf(v[c].y - mx1);
      if ((c % 3) == 0)      { a0 += (double)e0f; b0 += (double)e1f; }
      else if ((c % 3) == 1) { a1 += (double)e0f; b1 += (double)e1f; }
      else                   { a2 += (double)e0f; b2 += (double)e1f; }
    }
    double lse0 = (double)mx0 + log(a0 + a1 + a2);
    double lse1 = (double)mx1 + log(b0 + b1 + b2);
    double2 lw; lw.x = lse0; lw.y = lse1;
    reinterpret_cast<double2*>(lse_out + (size_t)b * N + n)[0] = lw;

#pragma unroll
    for (int c = 0; c < C1; ++c) {
      double s0d = (double)v[c + 1].x - lse0;
      double s1d = (double)v[c + 1].y - lse1;
      uint k0 = 0, k1 = 0;
      if (s0d > s_logth[c]) k0 = q_key16((float)s0d);
      if (s1d > s_logth[c]) k1 = q_key16((float)s1d);
      *reinterpret_cast<uint*>(keys_out + ((size_t)b * C1 + c) * npad + n)
          = k0 | (k1 << 16);
      if (k0) atomicAdd(&lhist[c * 256 + (k0 >> 8)], 1u);
      if (k1) atomicAdd(&lhist[c * 256 + (k1 >> 8)], 1u);
    }
  }
  if (j == NSPLIT - 1 && npad > N) {
    int pad = npad - N;
    for (int t = tid; t < pad * C1; t += NT) {
      int c = t / pad, n = N + (t - c * pad);
      keys_out[((size_t)b * C1 + c) * npad + n] = 0;
    }
  }
  __syncthreads();
  for (int i = tid; i < C1 * 256; i += NT) {
    uint v2 = lhist[i];
    if (v2) atomicAdd(&ghist[((size_t)b * C1 + (i >> 8)) * 256 + (i & 255)], v2);
  }
}

// ---- K2: inline walk + distributed collect (B*C1*SEGS blocks, u16 keys) ------
__global__ __launch_bounds__(NT) void collect_kernel(
    const u16* __restrict__ keys, const uint* __restrict__ ghist,
    uint4* __restrict__ L0cnt, uint* __restrict__ cand, uint* __restrict__ cnts,
    int npad)
{
  int blk = blockIdx.x;
  int task = blk >> 2, seg = blk & (SEGS - 1);
  int tid = threadIdx.x, lane = tid & 63;
  __shared__ uint sL, sCnt0, sCnt;

  if (tid < 64) {
    uint4 h = reinterpret_cast<const uint4*>(ghist + (size_t)task * 256)[tid];
    uint s = h.x + h.y + h.z + h.w;
    uint suf = s;
#pragma unroll
    for (int off = 1; off < 64; off <<= 1) {
      uint o = (uint)__shfl_down((int)suf, off);
      if (lane + off < 64) suf += o;
    }
    uint total = (uint)__shfl((int)suf, 0);
    uint sn = (uint)__shfl_down((int)suf, 1);
    if (lane == 63) sn = 0;
    uint c3 = h.w + sn, c2 = c3 + h.z, c1 = c2 + h.y, c0 = c1 + h.x;
    uint binoff, cnt, abv;
    if (c3 >= KTOP)      { binoff = 3; cnt = c3; abv = c3 - h.w; }
    else if (c2 >= KTOP) { binoff = 2; cnt = c2; abv = c2 - h.z; }
    else if (c1 >= KTOP) { binoff = 1; cnt = c1; abv = c1 - h.y; }
    else                 { binoff = 0; cnt = c0; abv = c0 - h.x; }
    uint L0v, cnt0v, abovev;
    if (total < KTOP) {
      L0v = 1u; cnt0v = total; abovev = 0u;
    } else {
      u64 m = __ballot(suf >= KTOP);
      int l = 63 - __clzll(m);
      uint bo = (uint)__shfl((int)binoff, l);
      cnt0v = (uint)__shfl((int)cnt, l);
      abovev = (uint)__shfl((int)abv, l);
      L0v = ((uint)(4 * l) + bo) << 8;
    }
    if (lane == 0) {
      sL = L0v; sCnt0 = cnt0v;
      if (seg == 0) L0cnt[task] = make_uint4(L0v, cnt0v, abovev, total);
    }
  }
  if (tid == NT - 1) sCnt = 0;
  __syncthreads();

  uint L = sL, cnt0 = sCnt0;
  if (cnt0 > CAPC) { if (tid == 0) cnts[blk] = 0; return; }   // slow path in F1

  const u16* krow = keys + (size_t)task * npad;
  const uint4* krow8 = reinterpret_cast<const uint4*>(krow);
  int nv8 = npad >> 3;
  int per8 = (nv8 + SEGS - 1) >> 2;
  int s8 = seg * per8, e8 = min(nv8, s8 + per8);
  uint* myc = cand + ((size_t)task * SEGS + seg) * SEGCAP;

  for (int i = s8 + tid; i < e8; i += NT) {
    uint4 kv = krow8[i];
    uint base = (uint)(i << 3);
    uint ks[8] = { kv.x & 0xFFFFu, kv.x >> 16, kv.y & 0xFFFFu, kv.y >> 16,
                   kv.z & 0xFFFFu, kv.z >> 16, kv.w & 0xFFFFu, kv.w >> 16 };
#pragma unroll
    for (int comp = 0; comp < 8; ++comp) {
      uint k = ks[comp];
      bool f = (k >= L);
      u64 m = __ballot(f);
      if (m) {
        uint nb = (uint)__popcll(m);
        uint wb = 0;
        if (lane == 0) wb = atomicAdd(&sCnt, nb);
        wb = (uint)__shfl((int)wb, 0);
        if (f) {
          uint pos = wb + (uint)__popcll(m & ((1ULL << lane) - 1ULL));
          if (pos < SEGCAP) myc[pos] = (k << 15) | (base + comp);
        }
      }
    }
  }
  __syncthreads();
  if (tid == 0) cnts[blk] = sCnt;      // actual (uncapped) count
}

// ---- K3: narrow -> gather+decode -> rank-sort -> mask -> resolve -> output ---
__global__ __launch_bounds__(NT) void final_kernel(
    const u16* __restrict__ keys, const uint4* __restrict__ L0cnt,
    const uint* __restrict__ candg, const uint* __restrict__ cnts,
    const float* __restrict__ scores, const double* __restrict__ lse,
    const float* __restrict__ bboxes, const float* __restrict__ dboxes,
    const float* __restrict__ scale_xy_p, const float* __restrict__ scale_wh_p,
    const float* __restrict__ nms_th_p,
    float* __restrict__ out, int B, int N, int npad)
{
  int task = blockIdx.x;
  int b = task / C1, c = task - b * C1;
  int tid = threadIdx.x, lane = tid & 63, wav = tid >> 6;
  const u16* krow = keys + (size_t)task * npad;
  int nv8 = npad >> 3;

  __shared__ uint cand[CAPC];            // 12 KB
  __shared__ uint histB[256];
  __shared__ uint scanB[256];
  __shared__ u64 wmB[4];
  __shared__ uint res3[4];
  __shared__ uint scq[SEGS];
  __shared__ int si[CAP];
  __shared__ u64 sC[CAP];
  __shared__ u64 skid[CAP];
  __shared__ float4 sbx[CAP];
  __shared__ float4 sbox[MROWS];
  __shared__ float sar[MROWS];
  __shared__ u64 smaskT[13][64];
  __shared__ u64 saliveW[4];
  __shared__ uint sCnt, sCnt2;

  uint4 w0 = L0cnt[task];
  uint cnt0 = w0.y;
  if (tid < SEGS) scq[tid] = cnts[task * SEGS + tid];
  if (tid == 0) { sCnt = 0; sCnt2 = 0; }
  if (tid < MROWS) { sbox[tid] = make_float4(0.f, 0.f, 0.f, 0.f); sar[tid] = 0.f; }
  __syncthreads();
  bool slow = (cnt0 > CAPC) ||
              (scq[0] > SEGCAP) || (scq[1] > SEGCAP) ||
              (scq[2] > SEGCAP) || (scq[3] > SEGCAP);

  uint pref = w0.x >> 8, above = w0.z, rank = KTOP - w0.z;
  uint cnt;

  if (!slow) {
    uint off1 = scq[0], off2 = off1 + scq[1], off3 = off2 + scq[2];
    cnt = off3 + scq[3];
    const uint* cg = candg + (size_t)task * SEGS * SEGCAP;
    for (int j = tid; j < (int)scq[0]; j += NT) cand[j] = cg[j];
    for (int j = tid; j < (int)scq[1]; j += NT) cand[off1 + j] = cg[SEGCAP + j];
    for (int j = tid; j < (int)scq[2]; j += NT) cand[off2 + j] = cg[2 * SEGCAP + j];
    for (int j = tid; j < (int)scq[3]; j += NT) cand[off3 + j] = cg[3 * SEGCAP + j];
    __syncthreads();
  } else {
    const uint4* krow8 = reinterpret_cast<const uint4*>(krow);
    histB[tid] = 0;
    __syncthreads();
    for (int i = tid; i < nv8; i += NT) {
      uint4 kv = krow8[i];
      uint ks[8] = { kv.x & 0xFFFFu, kv.x >> 16, kv.y & 0xFFFFu, kv.y >> 16,
                     kv.z & 0xFFFFu, kv.z >> 16, kv.w & 0xFFFFu, kv.w >> 16 };
#pragma unroll
      for (int comp = 0; comp < 8; ++comp) {
        uint k = ks[comp];
        if ((k >> 8) == pref) atomicAdd(&histB[k & 255u], 1u);
      }
    }
    __syncthreads();
    par_walk(histB, scanB, wmB, res3, rank, tid);
    uint Ts = (pref << 8) | res3[0];
    for (int i = tid; i < nv8; i += NT) {
      uint4 kv = krow8[i];
      uint base = (uint)(i << 3);
      uint ks[8] = { kv.x & 0xFFFFu, kv.x >> 16, kv.y & 0xFFFFu, kv.y >> 16,
                     kv.z & 0xFFFFu, kv.z >> 16, kv.w & 0xFFFFu, kv.w >> 16 };
#pragma unroll
      for (int comp = 0; comp < 8; ++comp) {
        uint k = ks[comp];
        bool f = (k >= Ts);
        u64 m = __ballot(f);
        if (m) {
          uint nb = (uint)__popcll(m);
          uint wb = 0;
          if (lane == 0) wb = atomicAdd(&sCnt, nb);
          wb = (uint)__shfl((int)wb, 0);
          if (f) {
            uint pos = wb + (uint)__popcll(m & ((1ULL << lane) - 1ULL));
            if (pos < CAPC) cand[pos] = (k << 15) | (base + comp);
          }
        }
      }
    }
    __syncthreads();
    cnt = min(sCnt, (uint)CAPC);
  }

  // ---------- narrow candidate list to <= CAP (one 256-bin level, exact key)
  uint cntF;
  if (cnt <= CAP) {
    for (int p = tid; p < (int)cnt; p += NT) si[p] = (int)(cand[p] & 0x7FFFu);
    __syncthreads();
    cntF = cnt;
  } else {
    histB[tid] = 0;
    __syncthreads();
    for (int p = tid; p < (int)cnt; p += NT) {
      uint k = cand[p] >> 15;
      if ((k >> 8) == pref) atomicAdd(&histB[k & 255u], 1u);
    }
    __syncthreads();
    par_walk(histB, scanB, wmB, res3, rank, tid);
    uint T = (pref << 8) | res3[0];
    for (int p = tid; p < (int)cnt; p += NT) {
      uint cd = cand[p];
      if ((cd >> 15) >= T) {
        uint q = atomicAdd(&sCnt2, 1u);
        if (q < CAP) si[q] = (int)(cd & 0x7FFFu);
      }
    }
    __syncthreads();
    cntF = min(sCnt2, (uint)CAP);
  }

  int valid_cnt = (int)min(cntF, (uint)KTOP);

  // ---------- gather f64 score + decode box inline; composite key
  {
    float sxy = *scale_xy_p, swh = *scale_wh_p;
    int p = tid;
    u64 C;
    if (p < (int)cntF) {
      int n = si[p];
      double s = (double)scores[((size_t)b * NCLS + (c + 1)) * N + n] - lse[(size_t)b * N + n];
      u64 f = flip64(s);
      C = (f & ~0x7FFFULL) | (u64)(32767 - n);
      const float* bb = bboxes + (size_t)b * 4 * N + n;
      float bx = bb[0];
      float by = bb[(size_t)N];
      float bw = bb[2 * (size_t)N];
      float bh = bb[3 * (size_t)N];
      float4 d = reinterpret_cast<const float4*>(dboxes)[n];
      float x = sxy * bx * d.z + d.x;
      float y = sxy * by * d.w + d.y;
      float w = expf(swh * bw) * d.z;
      float h = expf(swh * bh) * d.w;
      sbx[p] = make_float4(x - 0.5f * w, y - 0.5f * h, x + 0.5f * w, y + 0.5f * h);
    } else {
      C = (u64)p;   // pads sort below all valid flipped keys
      sbx[p] = make_float4(0.f, 0.f, 0.f, 0.f);
    }
    sC[p] = C;
  }
  __syncthreads();

  // ---------- rank-sort (single u64 compare); scatter into rank order
  {
    u64 kp = sC[tid];
    int r = 0;
#pragma unroll 8
    for (int jj = 0; jj < CAP; ++jj) r += (sC[jj] > kp) ? 1 : 0;
    if (tid < (int)cntF && r < KTOP) {
      skid[r] = kp;
      float4 bx = sbx[tid];
      sbox[r] = bx;
      sar[r] = fmaxf(bx.z - bx.x, 0.f) * fmaxf(bx.w - bx.y, 0.f);
    }
  }
  __syncthreads();

  float nth = *nms_th_p;

  // ---------- register-blocked suppression mask, transposed-native
  {
    float4 jb0 = sbox[lane], jb1 = sbox[lane + 64], jb2 = sbox[lane + 128];
    float4 jb3 = (lane + 192 < MROWS) ? sbox[lane + 192]
                                      : make_float4(0.f, 0.f, 0.f, 0.f);
    float ja0 = sar[lane], ja1 = sar[lane + 64], ja2 = sar[lane + 128],
          ja3 = (lane + 192 < MROWS) ? sar[lane + 192] : 0.f;
    for (int w = wav; w < 13; w += 4) {
      u64 word = 0;
      int r0 = w * 16;
#pragma unroll
      for (int rr = 0; rr < 16; ++rr) {
        int r = r0 + rr;
        float4 rb = sbox[r];
        float ra = sar[r];
        uint nib = 0;
#define IOU_BIT(K, JB, JA) { \
        int j = lane + 64 * (K); \
        float xx1 = fmaxf(rb.x, JB.x), yy1 = fmaxf(rb.y, JB.y); \
        float xx2 = fminf(rb.z, JB.z), yy2 = fminf(rb.w, JB.w); \
        float ww = fmaxf(xx2 - xx1, 0.f), hh = fmaxf(yy2 - yy1, 0.f); \
        float inter = ww * hh; \
        float den = ((ra + JA) - inter) + 1e-9f; \
        if ((inter >= nth * den) && (j > r)) nib |= 1u << (K); }
        IOU_BIT(0, jb0, ja0) IOU_BIT(1, jb1, ja1)
        IOU_BIT(2, jb2, ja2) IOU_BIT(3, jb3, ja3)
#undef IOU_BIT
        word |= (u64)nib << (rr * 4);
      }
      smaskT[w][lane] = word;
    }
  }
  __syncthreads();

  // ---------- greedy resolve: wave 0, masks in registers, in-lane unrolled
  if (tid < 64) {
    u64 mm[13];
#pragma unroll
    for (int w = 0; w < 13; ++w) mm[w] = smaskT[w][lane];
    uint av = 0;
#pragma unroll
    for (int k = 0; k < 4; ++k)
      if (lane + 64 * k < valid_cnt) av |= 1u << k;
#define STEP(i) { \
    u64 bm = __ballot((lane == ((i) & 63)) && ((av >> ((i) >> 6)) & 1u)); \
    if (bm) av &= ~((uint)((mm[(i) >> 4] >> (((i) & 15) * 4)) & 0xFULL)); }
#define S4(i)  STEP(i) STEP((i)+1) STEP((i)+2) STEP((i)+3)
#define S16(i) S4(i) S4((i)+4) S4((i)+8) S4((i)+12)
#define S64(i) S16(i) S16((i)+16) S16((i)+32) S16((i)+48)
    S64(0) S64(64) S64(128) S16(192)
#undef S64
#undef S16
#undef S4
#undef STEP
#pragma unroll
    for (int k = 0; k < 4; ++k) {
      u64 bb2 = __ballot((av >> k) & 1u);
      if (lane == 0) saliveW[k] = bb2;
    }
  }
  __syncthreads();

  // ---------- outputs: boxes | labels | scores | keep
  size_t M = (size_t)C1 * KTOP;
  float* out_boxes  = out;
  float* out_labels = out + (size_t)B * M * 4;
  float* out_scores = out_labels + (size_t)B * M;
  float* out_keep   = out_scores + (size_t)B * M;
  if (tid < KTOP) {
    size_t slot = ((size_t)b * C1 + c) * KTOP + tid;
    bool kept = (tid < valid_cnt) && ((saliveW[tid >> 6] >> (tid & 63)) & 1ULL);
    float4 bx = kept ? sbox[tid] : make_float4(0.f, 0.f, 0.f, 0.f);
    reinterpret_cast<float4*>(out_boxes)[slot] = bx;
    out_labels[slot] = kept ? (float)(c + 1) : 0.0f;
    out_scores[slot] = kept ? (float)exp(unflip64(skid[tid])) : 0.0f;
    out_keep[slot]   = kept ? 1.0f : 0.0f;
  }
}

extern "C" void kernel_launch(void* const* d_in, const int* in_sizes, int n_in,
                              void* d_out, int out_size, void* d_ws, size_t ws_size,
                              hipStream_t stream) {
  const float* bboxes   = (const float*)d_in[0];
  const float* scores   = (const float*)d_in[1];
  const float* dboxes   = (const float*)d_in[2];
  const float* conf_th  = (const float*)d_in[3];
  const float* nms_th   = (const float*)d_in[4];
  const float* scale_xy = (const float*)d_in[6];
  const float* scale_wh = (const float*)d_in[7];

  int N = in_sizes[2] / 4;
  int B = in_sizes[0] / (4 * N);
  int npad = (N + 7) & ~7;

  // ws: lse | keys(u16) | ghist(compact) | L0cnt | cand(u32) | cnts
  char* ws = (char*)d_ws;
  size_t off = 0;
  double* lse     = (double*)(ws + off); off += (size_t)B * N * 8;
  u16*    keys    = (u16*)   (ws + off); off += (size_t)B * C1 * npad * 2;
  uint*   ghist   = (uint*)  (ws + off); off += (size_t)B * C1 * 256 * 4;
  uint4*  L0cnt   = (uint4*) (ws + off); off += (size_t)B * C1 * 16;
  uint*   cand    = (uint*)  (ws + off); off += (size_t)B * C1 * SEGS * SEGCAP * 4;
  uint*   cnts    = (uint*)  (ws + off);

  zero_ghist<<<B * C1, NT, 0, stream>>>(ghist);   // 640 blocks x 256 = B*C1*256

  int perblk = ((N + NSPLIT - 1) / NSPLIT + 1) & ~1;   // even
  prep_kernel<<<B * NSPLIT, NT, 0, stream>>>(
      scores, conf_th, lse, keys, ghist, B, N, npad, perblk);

  collect_kernel<<<B * C1 * SEGS, NT, 0, stream>>>(
      keys, ghist, L0cnt, cand, cnts, npad);

  final_kernel<<<B * C1, NT, 0, stream>>>(
      keys, L0cnt, cand, cnts, scores, lse, bboxes, dboxes,
      scale_xy, scale_wh, nms_th, (float*)d_out, B, N, npad);
}

// Round 14
// 92.444 us; speedup vs baseline: 1.0610x; 1.0120x over previous
//
#include <hip/hip_runtime.h>
#include <math.h>

typedef unsigned int uint;
typedef unsigned short u16;
typedef unsigned long long u64;

#define NT 256
#define KTOP 200
#define CAP 256      // final candidate cap == NT (rank-sort)
#define CAPC 3072    // LDS candidate-list cap
#define SEGS 4       // collect segments per task
#define SEGCAP 512   // per-segment candidate cap in global
#define NCLS 21
#define C1 20
#define MROWS 208
#define NSPLIT 48    // prep blocks per batch image

struct Rec { float4 box; double lse; double pad; };   // 32 B

__device__ __forceinline__ u64 flip64(double d) {
  u64 u = (u64)__double_as_longlong(d);
  return (u & 0x8000000000000000ULL) ? ~u : (u | 0x8000000000000000ULL);
}

__device__ __forceinline__ double unflip64(u64 k) {
  u64 u = (k & 0x8000000000000000ULL) ? (k ^ 0x8000000000000000ULL) : ~k;
  return __longlong_as_double((long long)u);
}

// monotone u16 fixed-point key for s = log prob; 0 = invalid
__device__ __forceinline__ uint q_key16(float sf) {
  float qf = (sf + 16.0f) * 4096.0f;
  qf = fmaxf(fminf(qf, 65535.0f), 1.0f);
  return (uint)qf;
}

// parallel 256-bin suffix-scan walk: bin = max j with S[j] >= rank.
__device__ __forceinline__ void par_walk(const uint* hist, uint* scan, u64* wm,
                                         uint* res, uint rank, int tid) {
  scan[tid] = hist[tid];
  __syncthreads();
#pragma unroll
  for (int off = 1; off < 256; off <<= 1) {
    uint v = scan[tid];
    uint a = (tid + off < 256) ? scan[tid + off] : 0u;
    __syncthreads();
    scan[tid] = v + a;
    __syncthreads();
  }
  u64 m = __ballot(scan[tid] >= rank);
  if ((tid & 63) == 0) wm[tid >> 6] = m;
  __syncthreads();
  if (tid == 0) {
    int bin = 0;
    for (int w = 3; w >= 0; --w) {
      if (wm[w]) { bin = w * 64 + (63 - __clzll(wm[w])); break; }
    }
    res[0] = (uint)bin;
    res[1] = scan[bin];
    res[2] = hist[bin];
  }
  __syncthreads();
}

// ---- K0: zero the compact hist ----------------------------------------------
__global__ __launch_bounds__(NT) void zero_ghist(uint* __restrict__ g) {
  g[(size_t)blockIdx.x * NT + threadIdx.x] = 0;
}

// ---- K1: box decode + LSE + u16 keys + record store + compact hist ----------
__global__ __launch_bounds__(NT) void prep_kernel(
    const float* __restrict__ bboxes, const float* __restrict__ scores,
    const float* __restrict__ dboxes, const float* __restrict__ conf_th,
    const float* __restrict__ scale_xy_p, const float* __restrict__ scale_wh_p,
    Rec* __restrict__ recs, u16* __restrict__ keys_out,
    uint* __restrict__ ghist,     // [B*C1, 256] compact
    int B, int N, int npad, int perblk)
{
  __shared__ double s_logth[C1];
  __shared__ uint lhist[C1 * 256];
  int tid = threadIdx.x;
  if (tid < C1) s_logth[tid] = log((double)conf_th[tid]);
  for (int i = tid; i < C1 * 256; i += NT) lhist[i] = 0;
  __syncthreads();

  int b = blockIdx.x / NSPLIT, j = blockIdx.x - b * NSPLIT;
  int s0 = j * perblk, e0 = min(N, s0 + perblk);
  int half = (e0 - s0) >> 1;
  float sxy = *scale_xy_p, swh = *scale_wh_p;

  for (int p = tid; p < half; p += NT) {
    int n = s0 + 2 * p;
    // box decode for the anchor pair
    const float* bb = bboxes + (size_t)b * 4 * N + n;
    float2 bx = *reinterpret_cast<const float2*>(bb);
    float2 by = *reinterpret_cast<const float2*>(bb + (size_t)N);
    float2 bw = *reinterpret_cast<const float2*>(bb + 2 * (size_t)N);
    float2 bh = *reinterpret_cast<const float2*>(bb + 3 * (size_t)N);
    float4 d0 = reinterpret_cast<const float4*>(dboxes)[n];
    float4 d1 = reinterpret_cast<const float4*>(dboxes)[n + 1];
    float x0 = sxy * bx.x * d0.z + d0.x;
    float y0 = sxy * by.x * d0.w + d0.y;
    float w0 = expf(swh * bw.x) * d0.z;
    float h0 = expf(swh * bh.x) * d0.w;
    float x1 = sxy * bx.y * d1.z + d1.x;
    float y1 = sxy * by.y * d1.w + d1.y;
    float w1 = expf(swh * bw.y) * d1.z;
    float h1 = expf(swh * bh.y) * d1.w;

    const float* sc = scores + (size_t)b * NCLS * N + n;
    float2 v[NCLS];
    float mx0 = -INFINITY, mx1 = -INFINITY;
#pragma unroll
    for (int c = 0; c < NCLS; ++c) {
      float2 t = *reinterpret_cast<const float2*>(sc + (size_t)c * N);
      v[c] = t;
      mx0 = fmaxf(mx0, t.x);
      mx1 = fmaxf(mx1, t.y);
    }
    double a0 = 0.0, a1 = 0.0, a2 = 0.0;
    double b0 = 0.0, b1 = 0.0, b2 = 0.0;
#pragma unroll
    for (int c = 0; c < NCLS; ++c) {
      float e0f = __expf(v[c].x - mx0);
      float e1f = __expf(v[c].y - mx1);
      if ((c % 3) == 0)      { a0 += (double)e0f; b0 += (double)e1f; }
      else if ((c % 3) == 1) { a1 += (double)e0f; b1 += (double)e1f; }
      else                   { a2 += (double)e0f; b2 += (double)e1f; }
    }
    double lse0 = (double)mx0 + log(a0 + a1 + a2);
    double lse1 = (double)mx1 + log(b0 + b1 + b2);

    int gid = b * N + n;
    Rec r0, r1;
    r0.box = make_float4(x0 - 0.5f * w0, y0 - 0.5f * h0, x0 + 0.5f * w0, y0 + 0.5f * h0);
    r0.lse = lse0; r0.pad = 0.0;
    r1.box = make_float4(x1 - 0.5f * w1, y1 - 0.5f * h1, x1 + 0.5f * w1, y1 + 0.5f * h1);
    r1.lse = lse1; r1.pad = 0.0;
    recs[gid] = r0;
    recs[gid + 1] = r1;

#pragma unroll
    for (int c = 0; c < C1; ++c) {
      double s0d = (double)v[c + 1].x - lse0;
      double s1d = (double)v[c + 1].y - lse1;
      uint k0 = 0, k1 = 0;
      if (s0d > s_logth[c]) k0 = q_key16((float)s0d);
      if (s1d > s_logth[c]) k1 = q_key16((float)s1d);
      *reinterpret_cast<uint*>(keys_out + ((size_t)b * C1 + c) * npad + n)
          = k0 | (k1 << 16);
      if (k0) atomicAdd(&lhist[c * 256 + (k0 >> 8)], 1u);
      if (k1) atomicAdd(&lhist[c * 256 + (k1 >> 8)], 1u);
    }
  }
  if (j == NSPLIT - 1 && npad > N) {
    int pad = npad - N;
    for (int t = tid; t < pad * C1; t += NT) {
      int c = t / pad, n = N + (t - c * pad);
      keys_out[((size_t)b * C1 + c) * npad + n] = 0;
    }
  }
  __syncthreads();
  for (int i = tid; i < C1 * 256; i += NT) {
    uint v2 = lhist[i];
    if (v2) atomicAdd(&ghist[((size_t)b * C1 + (i >> 8)) * 256 + (i & 255)], v2);
  }
}

// ---- K2: inline walk + distributed collect (B*C1*SEGS blocks, u16 keys) ------
__global__ __launch_bounds__(NT) void collect_kernel(
    const u16* __restrict__ keys, const uint* __restrict__ ghist,
    uint4* __restrict__ L0cnt, uint* __restrict__ cand, uint* __restrict__ cnts,
    int npad)
{
  int blk = blockIdx.x;
  int task = blk >> 2, seg = blk & (SEGS - 1);
  int tid = threadIdx.x, lane = tid & 63;
  __shared__ uint sL, sCnt0, sCnt;

  if (tid < 64) {
    uint4 h = reinterpret_cast<const uint4*>(ghist + (size_t)task * 256)[tid];
    uint s = h.x + h.y + h.z + h.w;
    uint suf = s;
#pragma unroll
    for (int off = 1; off < 64; off <<= 1) {
      uint o = (uint)__shfl_down((int)suf, off);
      if (lane + off < 64) suf += o;
    }
    uint total = (uint)__shfl((int)suf, 0);
    uint sn = (uint)__shfl_down((int)suf, 1);
    if (lane == 63) sn = 0;
    uint c3 = h.w + sn, c2 = c3 + h.z, c1 = c2 + h.y, c0 = c1 + h.x;
    uint binoff, cnt, abv;
    if (c3 >= KTOP)      { binoff = 3; cnt = c3; abv = c3 - h.w; }
    else if (c2 >= KTOP) { binoff = 2; cnt = c2; abv = c2 - h.z; }
    else if (c1 >= KTOP) { binoff = 1; cnt = c1; abv = c1 - h.y; }
    else                 { binoff = 0; cnt = c0; abv = c0 - h.x; }
    uint L0v, cnt0v, abovev;
    if (total < KTOP) {
      L0v = 1u; cnt0v = total; abovev = 0u;
    } else {
      u64 m = __ballot(suf >= KTOP);
      int l = 63 - __clzll(m);
      uint bo = (uint)__shfl((int)binoff, l);
      cnt0v = (uint)__shfl((int)cnt, l);
      abovev = (uint)__shfl((int)abv, l);
      L0v = ((uint)(4 * l) + bo) << 8;
    }
    if (lane == 0) {
      sL = L0v; sCnt0 = cnt0v;
      if (seg == 0) L0cnt[task] = make_uint4(L0v, cnt0v, abovev, total);
    }
  }
  if (tid == NT - 1) sCnt = 0;
  __syncthreads();

  uint L = sL, cnt0 = sCnt0;
  if (cnt0 > CAPC) { if (tid == 0) cnts[blk] = 0; return; }   // slow path in K3

  const u16* krow = keys + (size_t)task * npad;
  const uint4* krow8 = reinterpret_cast<const uint4*>(krow);
  int nv8 = npad >> 3;
  int per8 = (nv8 + SEGS - 1) >> 2;
  int s8 = seg * per8, e8 = min(nv8, s8 + per8);
  uint* myc = cand + ((size_t)task * SEGS + seg) * SEGCAP;

  for (int i = s8 + tid; i < e8; i += NT) {
    uint4 kv = krow8[i];
    uint base = (uint)(i << 3);
    uint ks[8] = { kv.x & 0xFFFFu, kv.x >> 16, kv.y & 0xFFFFu, kv.y >> 16,
                   kv.z & 0xFFFFu, kv.z >> 16, kv.w & 0xFFFFu, kv.w >> 16 };
#pragma unroll
    for (int comp = 0; comp < 8; ++comp) {
      uint k = ks[comp];
      bool f = (k >= L);
      u64 m = __ballot(f);
      if (m) {
        uint nb = (uint)__popcll(m);
        uint wb = 0;
        if (lane == 0) wb = atomicAdd(&sCnt, nb);
        wb = (uint)__shfl((int)wb, 0);
        if (f) {
          uint pos = wb + (uint)__popcll(m & ((1ULL << lane) - 1ULL));
          if (pos < SEGCAP) myc[pos] = (k << 15) | (base + comp);
        }
      }
    }
  }
  __syncthreads();
  if (tid == 0) cnts[blk] = sCnt;      // actual (uncapped) count
}

// ---- K3: narrow -> gather (2 lines/cand) -> rank-sort -> mask -> resolve -----
__global__ __launch_bounds__(NT) void final_kernel(
    const u16* __restrict__ keys, const uint4* __restrict__ L0cnt,
    const uint* __restrict__ candg, const uint* __restrict__ cnts,
    const float* __restrict__ scores, const Rec* __restrict__ recs,
    const float* __restrict__ nms_th_p,
    float* __restrict__ out, int B, int N, int npad)
{
  int task = blockIdx.x;
  int b = task / C1, c = task - b * C1;
  int tid = threadIdx.x, lane = tid & 63, wav = tid >> 6;
  const u16* krow = keys + (size_t)task * npad;
  int nv8 = npad >> 3;

  __shared__ uint cand[CAPC];            // 12 KB
  __shared__ uint histB[256];
  __shared__ uint scanB[256];
  __shared__ u64 wmB[4];
  __shared__ uint res3[4];
  __shared__ uint scq[SEGS];
  __shared__ int si[CAP];
  __shared__ u64 sC[CAP];
  __shared__ u64 skid[CAP];
  __shared__ float4 sbx[CAP];
  __shared__ float4 sbox[MROWS];
  __shared__ float sar[MROWS];
  __shared__ u64 smaskT[13][64];
  __shared__ u64 saliveW[4];
  __shared__ uint sCnt, sCnt2;

  uint4 w0 = L0cnt[task];
  uint cnt0 = w0.y;
  if (tid < SEGS) scq[tid] = cnts[task * SEGS + tid];
  if (tid == 0) { sCnt = 0; sCnt2 = 0; }
  if (tid < MROWS) { sbox[tid] = make_float4(0.f, 0.f, 0.f, 0.f); sar[tid] = 0.f; }
  __syncthreads();
  bool slow = (cnt0 > CAPC) ||
              (scq[0] > SEGCAP) || (scq[1] > SEGCAP) ||
              (scq[2] > SEGCAP) || (scq[3] > SEGCAP);

  uint pref = w0.x >> 8, above = w0.z, rank = KTOP - w0.z;
  uint cnt;

  if (!slow) {
    uint off1 = scq[0], off2 = off1 + scq[1], off3 = off2 + scq[2];
    cnt = off3 + scq[3];
    const uint* cg = candg + (size_t)task * SEGS * SEGCAP;
    for (int j = tid; j < (int)scq[0]; j += NT) cand[j] = cg[j];
    for (int j = tid; j < (int)scq[1]; j += NT) cand[off1 + j] = cg[SEGCAP + j];
    for (int j = tid; j < (int)scq[2]; j += NT) cand[off2 + j] = cg[2 * SEGCAP + j];
    for (int j = tid; j < (int)scq[3]; j += NT) cand[off3 + j] = cg[3 * SEGCAP + j];
    __syncthreads();
  } else {
    const uint4* krow8 = reinterpret_cast<const uint4*>(krow);
    histB[tid] = 0;
    __syncthreads();
    for (int i = tid; i < nv8; i += NT) {
      uint4 kv = krow8[i];
      uint ks[8] = { kv.x & 0xFFFFu, kv.x >> 16, kv.y & 0xFFFFu, kv.y >> 16,
                     kv.z & 0xFFFFu, kv.z >> 16, kv.w & 0xFFFFu, kv.w >> 16 };
#pragma unroll
      for (int comp = 0; comp < 8; ++comp) {
        uint k = ks[comp];
        if ((k >> 8) == pref) atomicAdd(&histB[k & 255u], 1u);
      }
    }
    __syncthreads();
    par_walk(histB, scanB, wmB, res3, rank, tid);
    uint Ts = (pref << 8) | res3[0];
    for (int i = tid; i < nv8; i += NT) {
      uint4 kv = krow8[i];
      uint base = (uint)(i << 3);
      uint ks[8] = { kv.x & 0xFFFFu, kv.x >> 16, kv.y & 0xFFFFu, kv.y >> 16,
                     kv.z & 0xFFFFu, kv.z >> 16, kv.w & 0xFFFFu, kv.w >> 16 };
#pragma unroll
      for (int comp = 0; comp < 8; ++comp) {
        uint k = ks[comp];
        bool f = (k >= Ts);
        u64 m = __ballot(f);
        if (m) {
          uint nb = (uint)__popcll(m);
          uint wb = 0;
          if (lane == 0) wb = atomicAdd(&sCnt, nb);
          wb = (uint)__shfl((int)wb, 0);
          if (f) {
            uint pos = wb + (uint)__popcll(m & ((1ULL << lane) - 1ULL));
            if (pos < CAPC) cand[pos] = (k << 15) | (base + comp);
          }
        }
      }
    }
    __syncthreads();
    cnt = min(sCnt, (uint)CAPC);
  }

  // ---------- narrow candidate list to <= CAP (one 256-bin level, exact key)
  uint cntF;
  if (cnt <= CAP) {
    for (int p = tid; p < (int)cnt; p += NT) si[p] = (int)(cand[p] & 0x7FFFu);
    __syncthreads();
    cntF = cnt;
  } else {
    histB[tid] = 0;
    __syncthreads();
    for (int p = tid; p < (int)cnt; p += NT) {
      uint k = cand[p] >> 15;
      if ((k >> 8) == pref) atomicAdd(&histB[k & 255u], 1u);
    }
    __syncthreads();
    par_walk(histB, scanB, wmB, res3, rank, tid);
    uint T = (pref << 8) | res3[0];
    for (int p = tid; p < (int)cnt; p += NT) {
      uint cd = cand[p];
      if ((cd >> 15) >= T) {
        uint q = atomicAdd(&sCnt2, 1u);
        if (q < CAP) si[q] = (int)(cd & 0x7FFFu);
      }
    }
    __syncthreads();
    cntF = min(sCnt2, (uint)CAP);
  }

  int valid_cnt = (int)min(cntF, (uint)KTOP);

  // ---------- gather: record (box+lse, 1-2 lines) + score (1 line)
  {
    int p = tid;
    u64 C;
    if (p < (int)cntF) {
      int n = si[p];
      const Rec* rc = recs + (size_t)b * N + n;
      float4 box = rc->box;
      double l = rc->lse;
      double s = (double)scores[((size_t)b * NCLS + (c + 1)) * N + n] - l;
      u64 f = flip64(s);
      C = (f & ~0x7FFFULL) | (u64)(32767 - n);
      sbx[p] = box;
    } else {
      C = (u64)p;   // pads sort below all valid flipped keys
      sbx[p] = make_float4(0.f, 0.f, 0.f, 0.f);
    }
    sC[p] = C;
  }
  __syncthreads();

  // ---------- rank-sort (single u64 compare); scatter into rank order
  {
    u64 kp = sC[tid];
    int r = 0;
#pragma unroll 8
    for (int jj = 0; jj < CAP; ++jj) r += (sC[jj] > kp) ? 1 : 0;
    if (tid < (int)cntF && r < KTOP) {
      skid[r] = kp;
      float4 bx = sbx[tid];
      sbox[r] = bx;
      sar[r] = fmaxf(bx.z - bx.x, 0.f) * fmaxf(bx.w - bx.y, 0.f);
    }
  }
  __syncthreads();

  float nth = *nms_th_p;

  // ---------- register-blocked suppression mask, transposed-native
  {
    float4 jb0 = sbox[lane], jb1 = sbox[lane + 64], jb2 = sbox[lane + 128];
    float4 jb3 = (lane + 192 < MROWS) ? sbox[lane + 192]
                                      : make_float4(0.f, 0.f, 0.f, 0.f);
    float ja0 = sar[lane], ja1 = sar[lane + 64], ja2 = sar[lane + 128],
          ja3 = (lane + 192 < MROWS) ? sar[lane + 192] : 0.f;
    for (int w = wav; w < 13; w += 4) {
      u64 word = 0;
      int r0 = w * 16;
#pragma unroll
      for (int rr = 0; rr < 16; ++rr) {
        int r = r0 + rr;
        float4 rb = sbox[r];
        float ra = sar[r];
        uint nib = 0;
#define IOU_BIT(K, JB, JA) { \
        int j = lane + 64 * (K); \
        float xx1 = fmaxf(rb.x, JB.x), yy1 = fmaxf(rb.y, JB.y); \
        float xx2 = fminf(rb.z, JB.z), yy2 = fminf(rb.w, JB.w); \
        float ww = fmaxf(xx2 - xx1, 0.f), hh = fmaxf(yy2 - yy1, 0.f); \
        float inter = ww * hh; \
        float den = ((ra + JA) - inter) + 1e-9f; \
        if ((inter >= nth * den) && (j > r)) nib |= 1u << (K); }
        IOU_BIT(0, jb0, ja0) IOU_BIT(1, jb1, ja1)
        IOU_BIT(2, jb2, ja2) IOU_BIT(3, jb3, ja3)
#undef IOU_BIT
        word |= (u64)nib << (rr * 4);
      }
      smaskT[w][lane] = word;
    }
  }
  __syncthreads();

  // ---------- greedy resolve: wave 0, masks in registers, in-lane unrolled
  if (tid < 64) {
    u64 mm[13];
#pragma unroll
    for (int w = 0; w < 13; ++w) mm[w] = smaskT[w][lane];
    uint av = 0;
#pragma unroll
    for (int k = 0; k < 4; ++k)
      if (lane + 64 * k < valid_cnt) av |= 1u << k;
#define STEP(i) { \
    u64 bm = __ballot((lane == ((i) & 63)) && ((av >> ((i) >> 6)) & 1u)); \
    if (bm) av &= ~((uint)((mm[(i) >> 4] >> (((i) & 15) * 4)) & 0xFULL)); }
#define S4(i)  STEP(i) STEP((i)+1) STEP((i)+2) STEP((i)+3)
#define S16(i) S4(i) S4((i)+4) S4((i)+8) S4((i)+12)
#define S64(i) S16(i) S16((i)+16) S16((i)+32) S16((i)+48)
    S64(0) S64(64) S64(128) S16(192)
#undef S64
#undef S16
#undef S4
#undef STEP
#pragma unroll
    for (int k = 0; k < 4; ++k) {
      u64 bb2 = __ballot((av >> k) & 1u);
      if (lane == 0) saliveW[k] = bb2;
    }
  }
  __syncthreads();

  // ---------- outputs: boxes | labels | scores | keep
  size_t M = (size_t)C1 * KTOP;
  float* out_boxes  = out;
  float* out_labels = out + (size_t)B * M * 4;
  float* out_scores = out_labels + (size_t)B * M;
  float* out_keep   = out_scores + (size_t)B * M;
  if (tid < KTOP) {
    size_t slot = ((size_t)b * C1 + c) * KTOP + tid;
    bool kept = (tid < valid_cnt) && ((saliveW[tid >> 6] >> (tid & 63)) & 1ULL);
    float4 bx = kept ? sbox[tid] : make_float4(0.f, 0.f, 0.f, 0.f);
    reinterpret_cast<float4*>(out_boxes)[slot] = bx;
    out_labels[slot] = kept ? (float)(c + 1) : 0.0f;
    out_scores[slot] = kept ? (float)exp(unflip64(skid[tid])) : 0.0f;
    out_keep[slot]   = kept ? 1.0f : 0.0f;
  }
}

extern "C" void kernel_launch(void* const* d_in, const int* in_sizes, int n_in,
                              void* d_out, int out_size, void* d_ws, size_t ws_size,
                              hipStream_t stream) {
  const float* bboxes   = (const float*)d_in[0];
  const float* scores   = (const float*)d_in[1];
  const float* dboxes   = (const float*)d_in[2];
  const float* conf_th  = (const float*)d_in[3];
  const float* nms_th   = (const float*)d_in[4];
  const float* scale_xy = (const float*)d_in[6];
  const float* scale_wh = (const float*)d_in[7];

  int N = in_sizes[2] / 4;
  int B = in_sizes[0] / (4 * N);
  int npad = (N + 7) & ~7;

  // ws: recs(32B) | keys(u16) | ghist(compact) | L0cnt | cand(u32) | cnts
  char* ws = (char*)d_ws;
  size_t off = 0;
  Rec*    recs    = (Rec*)   (ws + off); off += (size_t)B * N * sizeof(Rec);
  u16*    keys    = (u16*)   (ws + off); off += (size_t)B * C1 * npad * 2;
  uint*   ghist   = (uint*)  (ws + off); off += (size_t)B * C1 * 256 * 4;
  uint4*  L0cnt   = (uint4*) (ws + off); off += (size_t)B * C1 * 16;
  uint*   cand    = (uint*)  (ws + off); off += (size_t)B * C1 * SEGS * SEGCAP * 4;
  uint*   cnts    = (uint*)  (ws + off);

  zero_ghist<<<B * C1, NT, 0, stream>>>(ghist);

  int perblk = ((N + NSPLIT - 1) / NSPLIT + 1) & ~1;   // even
  prep_kernel<<<B * NSPLIT, NT, 0, stream>>>(
      bboxes, scores, dboxes, conf_th, scale_xy, scale_wh,
      recs, keys, ghist, B, N, npad, perblk);

  collect_kernel<<<B * C1 * SEGS, NT, 0, stream>>>(
      keys, ghist, L0cnt, cand, cnts, npad);

  final_kernel<<<B * C1, NT, 0, stream>>>(
      keys, L0cnt, cand, cnts, scores, recs, nms_th,
      (float*)d_out, B, N, npad);
}